// Round 4
// baseline (405.018 us; speedup 1.0000x reference)
//
#include <hip/hip_runtime.h>
#include <math.h>

#define B_    4
#define T_    8192
#define C_    1024
#define E_    64
#define NTOK  (B_*T_)          // 32768
#define KSEL  2

// d_out offsets (in floats): idx, scores, probs, importance, load
#define OFF_IDX    0
#define OFF_SCORES (NTOK*KSEL)               // 65536
#define OFF_PROBS  (2*NTOK*KSEL)             // 131072
#define OFF_IMP    (OFF_PROBS + NTOK*E_)     // 2228224
#define OFF_LOAD   (OFF_IMP + E_)            // 2228288

// workspace offsets (bytes)
#define WS_W64    0                          // 2048*64*8 = 1 MB (fp64 atomic accum)
#define WS_W32    1048576                    // 1024*64*4 = 256 KB ([d][e], refine)
#define WS_BSWH   1310720                    // 128 KB bf16 hi, MFMA-frag order
#define WS_BSWL   1441792                    // 128 KB bf16 lo
#define WS_LB64   1572864                    // 4*64*8 = 2 KB
#define WS_LB32   1574912                    // 4*64*4 = 1 KB
#define WS_CNT    1575936                    // 4
#define WS_LIST   1576448                    // REFINE_CAP*4 = 32 KB

#define REFINE_CAP 8192
#define REFINE_EPS 3e-4f

typedef __attribute__((ext_vector_type(8))) short short8;
typedef __attribute__((ext_vector_type(4))) float f32x4;

// ---------------------------------------------------------------------------
// K1: w64[d][e] += sum_{c chunk} Wc[c][d] * Wg[e][c], d in 0..2047 (fp64).
// d<1024 -> Wcomb (x path); d>=1024 -> V (cond path).
// grid: 32 d-tiles x 8 c-chunks = 256 blocks. Also zeroes ref_cnt/imp/load.
// ---------------------------------------------------------------------------
__global__ __launch_bounds__(256) void k_comb(const float* __restrict__ Wg,
                                              const float* __restrict__ Wc,
                                              double* __restrict__ w64,
                                              float* __restrict__ out,
                                              unsigned int* __restrict__ ref_cnt) {
    __shared__ float wc_s[64 * 64];   // [c][d_local]
    __shared__ float wg_s[64 * 64];   // [c][e]  (transposed at stage time)
    const int tid   = threadIdx.x;
    const int e     = tid & 63;
    const int dg    = tid >> 6;                    // 0..3 (wave-uniform)
    const int dtile = (blockIdx.x & 31) * 64;
    const int cbase = (blockIdx.x >> 5) * 128;

    if (blockIdx.x == 0) {                         // fold small zero-inits here
        if (tid < 2 * E_) out[OFF_IMP + tid] = 0.f;
        if (tid == 2 * E_) *ref_cnt = 0u;
    }

    double acc[16];
#pragma unroll
    for (int i = 0; i < 16; ++i) acc[i] = 0.0;

    for (int cc = 0; cc < 128; cc += 64) {
        const int c0 = cbase + cc;
        __syncthreads();
#pragma unroll
        for (int k = 0; k < 4; ++k) {
            int li = tid + k * 256;
            int r = li >> 4, c4 = (li & 15) * 4;
            *(float4*)&wc_s[r * 64 + c4] =
                *(const float4*)&Wc[(size_t)(c0 + r) * 2048 + dtile + c4];
        }
#pragma unroll
        for (int k = 0; k < 4; ++k) {
            int li = tid + k * 256;
            int r = li >> 4, c4 = (li & 15) * 4;
            float4 v = *(const float4*)&Wg[(size_t)r * 1024 + c0 + c4];
            wg_s[(c4 + 0) * 64 + r] = v.x;
            wg_s[(c4 + 1) * 64 + r] = v.y;
            wg_s[(c4 + 2) * 64 + r] = v.z;
            wg_s[(c4 + 3) * 64 + r] = v.w;
        }
        __syncthreads();
        for (int c = 0; c < 64; ++c) {
            double wg = (double)wg_s[c * 64 + e];
            const float* wcrow = &wc_s[c * 64 + dg * 16];
#pragma unroll
            for (int i = 0; i < 16; ++i)
                acc[i] += wg * (double)wcrow[i];
        }
    }
#pragma unroll
    for (int i = 0; i < 16; ++i) {
        double* p = &w64[(size_t)(dtile + dg * 16 + i) * 64 + e];
#if __has_builtin(__builtin_amdgcn_global_atomic_fadd_f64)
        unsafeAtomicAdd(p, acc[i]);
#else
        atomicAdd(p, acc[i]);
#endif
    }
}

// ---------------------------------------------------------------------------
// K2: finalize. blocks 0..255: e = blk&63, d-quarter = blk>>6 -> wcomb32[d][e]
// + bf16 hi/lo split into MFMA-frag-swizzled bswH/bswL: slab s = kchunk*4+et
// holds 512 shorts, element (lane=qsel*16+nn, j) at s*512 + lane*8 + j.
// blocks 256..259: lbias[b][e] (fp64) from V-half of w64.
// ---------------------------------------------------------------------------
__global__ __launch_bounds__(256) void k_finalize(const double* __restrict__ w64,
                                                  const float* __restrict__ cond,
                                                  float* __restrict__ wcomb32,
                                                  short* __restrict__ bswH,
                                                  short* __restrict__ bswL,
                                                  double* __restrict__ lbias64,
                                                  float* __restrict__ lbias32) {
    const int tid = threadIdx.x;
    if (blockIdx.x < 256) {
        const int e  = blockIdx.x & 63;
        const int dq = blockIdx.x >> 6;
        const int et = e >> 4, nn = e & 15;
        const int d  = dq * 256 + tid;
        float f = (float)w64[(size_t)d * 64 + e];
        wcomb32[d * 64 + e] = f;
        unsigned u = __float_as_uint(f);
        short hi = (short)(u >> 16);
        float r = f - __uint_as_float(u & 0xFFFF0000u);
        short lo = (short)(__float_as_uint(r) >> 16);
        int kchunk = d >> 5, qsel = (d >> 3) & 3, j = d & 7;
        int idx = ((kchunk * 4 + et) * 64 + qsel * 16 + nn) * 8 + j;
        bswH[idx] = hi;
        bswL[idx] = lo;
    } else {
        const int b = blockIdx.x - 256;
        const int e = tid & 63, part = tid >> 6;
        double acc = 0.0;
        const int d0 = part * 256;
        for (int d = d0; d < d0 + 256; ++d)
            acc += (double)cond[b * 1024 + d] * w64[(size_t)(1024 + d) * 64 + e];
        __shared__ double red[256];
        red[tid] = acc;
        __syncthreads();
        if (tid < 64) {
            double s = red[tid] + red[tid + 64] + red[tid + 128] + red[tid + 192];
            lbias64[b * 64 + tid] = s;
            lbias32[b * 64 + tid] = (float)s;
        }
    }
}

// ---------------------------------------------------------------------------
// split 8 consecutive floats into bf16 hi (truncate) + bf16 lo (residual),
// loading x with NON-TEMPORAL loads (x is stream-once data).
// ---------------------------------------------------------------------------
__device__ __forceinline__ void cvt_split8_nt(const float* __restrict__ p,
                                              short8& h, short8& l) {
    f32x4 v0 = __builtin_nontemporal_load((const f32x4*)p);
    f32x4 v1 = __builtin_nontemporal_load(((const f32x4*)p) + 1);
    float xv[8] = {v0[0], v0[1], v0[2], v0[3], v1[0], v1[1], v1[2], v1[3]};
#pragma unroll
    for (int j = 0; j < 8; ++j) {
        unsigned u = __float_as_uint(xv[j]);
        h[j] = (short)(u >> 16);
        float r = xv[j] - __uint_as_float(u & 0xFFFF0000u);
        l[j] = (short)(__float_as_uint(r) >> 16);
    }
}

// ---------------------------------------------------------------------------
// K_main: logits = x @ Wcomb + lbias[b], bf16-split MFMA, K-split x4 in-block.
// 2048 blocks x 256 thr; block = 16 tokens; wave w owns K range [w*256,+256).
// Wave tile: 16 tok (1 A-frag) x 64 exp (4 et). 8 blocks/CU -> 32 waves/CU.
// A/B frag: [m|n = lane&15][k = (lane>>4)*8 + j]; C/D: col=lane&15 (n),
// row=(lane>>4)*4+reg (m).
// ---------------------------------------------------------------------------
#define MT    16
#define ROWP  65          // accbuf row stride (pad breaks 64-stride banks)

__global__ __launch_bounds__(256, 8) void k_main(const float* __restrict__ x,
                                                 const short* __restrict__ bswH,
                                                 const short* __restrict__ bswL,
                                                 const float* __restrict__ lbias32,
                                                 float* __restrict__ out,
                                                 unsigned int* __restrict__ ref_cnt,
                                                 int* __restrict__ ref_list) {
    __shared__ float accbuf[4 * MT * ROWP];   // 16.6 KB: [w][tok][e] partials
    __shared__ float invs[MT];
    __shared__ unsigned int cnts[E_];

    const int tid    = threadIdx.x;
    const int wid    = tid >> 6;
    const int lane   = tid & 63;
    const int nn     = lane & 15;
    const int qsel   = lane >> 4;
    const int token0 = blockIdx.x * MT;
    const int b      = token0 >> 13;          // /8192

    if (tid < E_) cnts[tid] = 0;

    f32x4 acc[4];
#pragma unroll
    for (int et = 0; et < 4; ++et) acc[et] = (f32x4){0.f, 0.f, 0.f, 0.f};

    // A pointer: this wave's K-quarter, lane's qsel sub-offset
    const float* a0 = x + (size_t)(token0 + nn) * 1024 + wid * 256 + qsel * 8;
    // B slabs: kchunk = wid*8 + kc; slab = kchunk*4 + et; 512 shorts per slab
    const short* bh0 = bswH + ((size_t)(wid * 8) * 4) * 512 + lane * 8;
    const short* bl0 = bswL + ((size_t)(wid * 8) * 4) * 512 + lane * 8;

#pragma unroll 2
    for (int kc = 0; kc < 8; ++kc) {
        short8 ah, al;
        cvt_split8_nt(a0 + kc * 32, ah, al);
        const short* bh = bh0 + (size_t)kc * 4 * 512;
        const short* bl = bl0 + (size_t)kc * 4 * 512;
#pragma unroll
        for (int et = 0; et < 4; ++et) {
            short8 b_h = *(const short8*)(bh + et * 512);
            short8 b_l = *(const short8*)(bl + et * 512);
            acc[et] = __builtin_amdgcn_mfma_f32_16x16x32_bf16(ah, b_h, acc[et], 0, 0, 0);
            acc[et] = __builtin_amdgcn_mfma_f32_16x16x32_bf16(ah, b_l, acc[et], 0, 0, 0);
            acc[et] = __builtin_amdgcn_mfma_f32_16x16x32_bf16(al, b_h, acc[et], 0, 0, 0);
        }
    }

    // dump partial accs: tok = qsel*4 + r, e = et*16 + nn
    const int q4 = qsel * 4;
#pragma unroll
    for (int et = 0; et < 4; ++et)
#pragma unroll
        for (int r = 0; r < 4; ++r)
            accbuf[wid * (MT * ROWP) + (q4 + r) * ROWP + et * 16 + nn] = acc[et][r];
    __syncthreads();

    // reduce K-quarters + lbias -> logits in accbuf[0] region
    for (int li = tid; li < MT * E_; li += 256) {
        int tok = li >> 6, e = li & 63;
        int o = tok * ROWP + e;
        float s = accbuf[o] + accbuf[MT * ROWP + o] + accbuf[2 * MT * ROWP + o] +
                  accbuf[3 * MT * ROWP + o] + lbias32[b * 64 + e];
        accbuf[o] = s;
    }
    __syncthreads();

    if (tid < MT) {
        const int t = tid;
        const int base = t * ROWP;
        float v1 = -1e30f, v2 = -1e30f, v3 = -1e30f;
        int i1 = 0, i2 = 0;
        for (int e = 0; e < E_; ++e) {
            float l = accbuf[base + e];
            if (l > v1)      { v3 = v2; v2 = v1; i2 = i1; v1 = l; i1 = e; }
            else if (l > v2) { v3 = v2; v2 = l; i2 = e; }
            else if (l > v3) { v3 = l; }
        }
        float sum = 0.f;
        for (int e = 0; e < E_; ++e) {
            float ex = __expf(accbuf[base + e] - v1);
            accbuf[base + e] = ex;
            sum += ex;
        }
        invs[t] = 1.0f / sum;

        const int gt = token0 + t;
        float s1 = 1.0f / (1.0f + __expf(v2 - v1));   // softmax over top-2
        *(float2*)&out[OFF_IDX + (size_t)gt * 2]    = make_float2((float)i1, (float)i2);
        *(float2*)&out[OFF_SCORES + (size_t)gt * 2] = make_float2(s1, 1.0f - s1);
        atomicAdd(&cnts[i1], 1u);
        atomicAdd(&cnts[i2], 1u);

        float g12 = v1 - v2, g23 = v2 - v3;
        float g = g12 < g23 ? g12 : g23;
        if (g < REFINE_EPS) {
            unsigned int pos = atomicAdd(ref_cnt, 1u);
            if (pos < REFINE_CAP) ref_list[pos] = gt;
        }
    }
    __syncthreads();

    // probs: 1024 floats = 256 float4, exactly one per thread
    {
        float* probs = out + OFF_PROBS + (size_t)token0 * E_;
        int tok = tid >> 4;
        int c4 = (tid & 15) << 2;
        float inv = invs[tok];
        int o = tok * ROWP + c4;
        *(float4*)&probs[(size_t)tid * 4] =
            make_float4(accbuf[o] * inv, accbuf[o + 1] * inv,
                        accbuf[o + 2] * inv, accbuf[o + 3] * inv);
    }

    // importance + load: one atomic each per e per block
    if (tid < E_) {
        const int e = tid;
        float s = 0.f;
        for (int t = 0; t < MT; ++t) s += accbuf[t * ROWP + e] * invs[t];
        atomicAdd(&out[OFF_IMP + e],  s * (1.0f / (float)NTOK));
        atomicAdd(&out[OFF_LOAD + e], (float)cnts[e] * (1.0f / (float)(NTOK * KSEL)));
    }
}

// ---------------------------------------------------------------------------
// K_ref: fp64 re-evaluation of ambiguous tokens. One wave per flagged token,
// lane = expert, 4 split accumulators.
// ---------------------------------------------------------------------------
__global__ __launch_bounds__(256) void k_refine(const float* __restrict__ x,
                                                const float* __restrict__ wcomb32,
                                                const double* __restrict__ lbias64,
                                                const unsigned int* __restrict__ ref_cnt,
                                                const int* __restrict__ ref_list,
                                                float* __restrict__ out) {
    int wave = (int)((blockIdx.x * blockDim.x + threadIdx.x) >> 6);
    int lane = threadIdx.x & 63;
    unsigned int n = *ref_cnt;
    if (n > REFINE_CAP) n = REFINE_CAP;
    const int nwaves = (int)((gridDim.x * blockDim.x) >> 6);

    for (unsigned int wi = wave; wi < n; wi += nwaves) {
        const int gt = ref_list[wi];
        const int b = gt / T_;
        const float* xrow = x + (size_t)gt * C_;
        double a0 = 0.0, a1 = 0.0, a2 = 0.0, a3 = 0.0;
        for (int d = 0; d < C_; d += 4) {
            a0 += (double)xrow[d + 0] * (double)wcomb32[(d + 0) * 64 + lane];
            a1 += (double)xrow[d + 1] * (double)wcomb32[(d + 1) * 64 + lane];
            a2 += (double)xrow[d + 2] * (double)wcomb32[(d + 2) * 64 + lane];
            a3 += (double)xrow[d + 3] * (double)wcomb32[(d + 3) * 64 + lane];
        }
        double acc = ((a0 + a1) + (a2 + a3)) + lbias64[b * 64 + lane];

        double v = acc; int id = lane;
        for (int off = 32; off > 0; off >>= 1) {
            double ov = __shfl_xor(v, off, 64);
            int oid   = __shfl_xor(id, off, 64);
            if (ov > v || (ov == v && oid < id)) { v = ov; id = oid; }
        }
        double v1 = v; int i1 = id;
        v = (lane == i1) ? -1e300 : acc; id = lane;
        for (int off = 32; off > 0; off >>= 1) {
            double ov = __shfl_xor(v, off, 64);
            int oid   = __shfl_xor(id, off, 64);
            if (ov > v || (ov == v && oid < id)) { v = ov; id = oid; }
        }
        double v2 = v; int i2 = id;

        if (lane == 0) {
            float s1 = (float)(1.0 / (1.0 + exp(v2 - v1)));
            *(float2*)&out[OFF_IDX + (size_t)gt * 2]    = make_float2((float)i1, (float)i2);
            *(float2*)&out[OFF_SCORES + (size_t)gt * 2] = make_float2(s1, 1.0f - s1);
        }
    }
}

// ---------------------------------------------------------------------------
extern "C" void kernel_launch(void* const* d_in, const int* in_sizes, int n_in,
                              void* d_out, int out_size, void* d_ws, size_t ws_size,
                              hipStream_t stream) {
    const float* x    = (const float*)d_in[0];   // (4,8192,1024)
    const float* cond = (const float*)d_in[1];   // (4,1024)
    const float* Wg   = (const float*)d_in[2];   // (64,1024)
    const float* Wc   = (const float*)d_in[3];   // (1024,2048)
    float* out = (float*)d_out;
    char*  ws  = (char*)d_ws;

    double* w64     = (double*)(ws + WS_W64);
    float*  wcomb32 = (float*)(ws + WS_W32);
    short*  bswH    = (short*)(ws + WS_BSWH);
    short*  bswL    = (short*)(ws + WS_BSWL);
    double* lbias64 = (double*)(ws + WS_LB64);
    float*  lbias32 = (float*)(ws + WS_LB32);
    unsigned int* ref_cnt = (unsigned int*)(ws + WS_CNT);
    int*    ref_list = (int*)(ws + WS_LIST);

    hipMemsetAsync(w64, 0, 2048 * 64 * sizeof(double), stream);

    k_comb<<<256, 256, 0, stream>>>(Wg, Wc, w64, out, ref_cnt);
    k_finalize<<<260, 256, 0, stream>>>(w64, cond, wcomb32, bswH, bswL, lbias64, lbias32);
    k_main<<<NTOK / MT, 256, 0, stream>>>(x, bswH, bswL, lbias32, out, ref_cnt, ref_list);
    k_refine<<<128, 256, 0, stream>>>(x, wcomb32, lbias64, ref_cnt, ref_list, out);
}

// Round 5
// 349.588 us; speedup vs baseline: 1.1586x; 1.1586x over previous
//
#include <hip/hip_runtime.h>
#include <math.h>

#define B_    4
#define T_    8192
#define C_    1024
#define E_    64
#define NTOK  (B_*T_)          // 32768
#define KSEL  2

// d_out offsets (in floats): idx, scores, probs, importance, load
#define OFF_IDX    0
#define OFF_SCORES (NTOK*KSEL)               // 65536
#define OFF_PROBS  (2*NTOK*KSEL)             // 131072
#define OFF_IMP    (OFF_PROBS + NTOK*E_)     // 2228224
#define OFF_LOAD   (OFF_IMP + E_)            // 2228288

// workspace offsets (bytes)
#define WS_W32    0                          // 1024*64*4 = 256 KB ([d][e], refine)
#define WS_BSWH   262144                     // 128 KB bf16 hi, MFMA-frag order
#define WS_BSWL   393216                     // 128 KB bf16 lo
#define WS_LB64   524288                     // 4*64*8 = 2 KB  (zeroed w/ CNT)
#define WS_CNT    526336                     // 4
#define WS_LIST   526400                     // REFINE_CAP*4 = 32 KB

#define REFINE_CAP 8192
#define REFINE_EPS 3e-4f

typedef __attribute__((ext_vector_type(8))) short short8;
typedef __attribute__((ext_vector_type(4))) float f32x4;

// ---------------------------------------------------------------------------
// K_prep: block bid owns 8 d's (d0=bid*8, d in 0..2047), full C in fp64.
// d<1024: wcomb32[d][e] + bf16 hi/lo split -> bsw slabs (MFMA-frag order:
//   slab s=kchunk*4+et holds 512 shorts, (lane=qsel*16+nn, j) at s*512+lane*8+j)
// d>=1024: partial lbias[b][e] contributions via fp64 atomics (pre-reduced).
// Block 0 also zeroes importance/load region of out.
// ---------------------------------------------------------------------------
__global__ __launch_bounds__(256) void k_prep(const float* __restrict__ Wg,
                                              const float* __restrict__ Wc,
                                              const float* __restrict__ cond,
                                              float* __restrict__ wcomb32,
                                              short* __restrict__ bswH,
                                              short* __restrict__ bswL,
                                              double* __restrict__ lbias64,
                                              float* __restrict__ out) {
    __shared__ float wg_s[64 * 64];   // [c][e]  (transposed at stage)
    __shared__ float wc_s[64 * 8];    // [c][d_local]
    __shared__ double red[256];

    const int tid = threadIdx.x;
    const int e   = tid & 63;
    const int dg  = tid >> 6;                  // 0..3
    const int d0  = blockIdx.x * 8;

    if (blockIdx.x == 0 && tid < 2 * E_) out[OFF_IMP + tid] = 0.f;

    double acc0 = 0.0, acc1 = 0.0;

    for (int c0 = 0; c0 < C_; c0 += 64) {
        __syncthreads();
        // stage Wg chunk transposed: wg_s[c][e]
#pragma unroll
        for (int k = 0; k < 4; ++k) {
            int li = tid + k * 256;
            int r = li >> 4, c4 = (li & 15) * 4;
            float4 v = *(const float4*)&Wg[(size_t)r * 1024 + c0 + c4];
            wg_s[(c4 + 0) * 64 + r] = v.x;
            wg_s[(c4 + 1) * 64 + r] = v.y;
            wg_s[(c4 + 2) * 64 + r] = v.z;
            wg_s[(c4 + 3) * 64 + r] = v.w;
        }
        // stage Wc column slab: wc_s[c][dl], 512 floats
        {
            int cc = tid >> 2, dd0 = (tid & 3) * 2;
            *(float2*)&wc_s[cc * 8 + dd0] =
                *(const float2*)&Wc[(size_t)(c0 + cc) * 2048 + d0 + dd0];
        }
        __syncthreads();
#pragma unroll 4
        for (int c = 0; c < 64; ++c) {
            double wg = (double)wg_s[c * 64 + e];
            acc0 += wg * (double)wc_s[c * 8 + dg * 2 + 0];
            acc1 += wg * (double)wc_s[c * 8 + dg * 2 + 1];
        }
    }

    if (d0 < 1024) {
        double av[2] = {acc0, acc1};
        const int et = e >> 4, nn = e & 15;
#pragma unroll
        for (int j2 = 0; j2 < 2; ++j2) {
            int d = d0 + dg * 2 + j2;
            float f = (float)av[j2];
            wcomb32[d * 64 + e] = f;
            unsigned u = __float_as_uint(f);
            short hi = (short)(u >> 16);
            float r = f - __uint_as_float(u & 0xFFFF0000u);
            short lo = (short)(__float_as_uint(r) >> 16);
            int kchunk = d >> 5, qsel = (d >> 3) & 3, j = d & 7;
            int idx = ((kchunk * 4 + et) * 64 + qsel * 16 + nn) * 8 + j;
            bswH[idx] = hi;
            bswL[idx] = lo;
        }
    } else {
        const int da = d0 - 1024 + dg * 2;
#pragma unroll
        for (int b = 0; b < 4; ++b) {
            double pb = (double)cond[b * 1024 + da] * acc0 +
                        (double)cond[b * 1024 + da + 1] * acc1;
            __syncthreads();
            red[tid] = pb;
            __syncthreads();
            if (tid < 64) {
                double s = red[tid] + red[tid + 64] + red[tid + 128] + red[tid + 192];
#if __has_builtin(__builtin_amdgcn_global_atomic_fadd_f64)
                unsafeAtomicAdd(&lbias64[b * 64 + tid], s);
#else
                atomicAdd(&lbias64[b * 64 + tid], s);
#endif
            }
        }
    }
}

// ---------------------------------------------------------------------------
// split 8 consecutive fp32 (from LDS-read registers) into bf16 hi + lo
// ---------------------------------------------------------------------------
__device__ __forceinline__ void split8(const float* xv, short8& h, short8& l) {
#pragma unroll
    for (int j = 0; j < 8; ++j) {
        unsigned u = __float_as_uint(xv[j]);
        h[j] = (short)(u >> 16);
        float r = xv[j] - __uint_as_float(u & 0xFFFF0000u);
        l[j] = (short)(__float_as_uint(r) >> 16);
    }
}

// ---------------------------------------------------------------------------
// K_main: logits = x @ Wcomb + lbias[b], bf16-split MFMA.
// 512 blocks x 256 thr; block = 64 tokens, wave = 16 tokens x 64 experts,
// full K per wave. x staged via LDS with PERFECTLY COALESCED global reads
// (consecutive lanes -> consecutive float4); A-frags read from LDS
// (row stride 132 floats -> 2-way bank alias, free). B direct from L2 slabs.
// A/B frag: [m|n=lane&15][k=(lane>>4)*8+j]; C/D: col=lane&15, row=(lane>>4)*4+r.
// ---------------------------------------------------------------------------
#define MT    64
#define XSTR  132         // LDS x-tile row stride in floats
#define ROWP  65          // epilogue logits row stride

__global__ __launch_bounds__(256, 2) void k_main(const float* __restrict__ x,
                                                 const short* __restrict__ bswH,
                                                 const short* __restrict__ bswL,
                                                 const double* __restrict__ lbias64,
                                                 float* __restrict__ out,
                                                 unsigned int* __restrict__ ref_cnt,
                                                 int* __restrict__ ref_list) {
    __shared__ float xs[MT * XSTR];   // 33.8 KB x-tile; reused for logits
    __shared__ float invs[MT];
    __shared__ unsigned int cnts[E_];

    const int tid    = threadIdx.x;
    const int wid    = tid >> 6;
    const int lane   = tid & 63;
    const int nn     = lane & 15;
    const int qsel   = lane >> 4;
    const int token0 = blockIdx.x * MT;
    const int b      = token0 >> 13;          // /8192

    if (tid < E_) cnts[tid] = 0;

    f32x4 acc[4];
#pragma unroll
    for (int et = 0; et < 4; ++et) acc[et] = (f32x4){0.f, 0.f, 0.f, 0.f};

    const int srow = tid >> 5;        // staging row pair base (2 rows/wave pass)
    const int scol = (tid & 31) * 4;  // staging float4 column

    for (int t = 0; t < 8; ++t) {     // K-tiles of 128
        const int k0 = t * 128;
        // ---- stage: 64 rows x 128 k, coalesced nt float4 loads ----
#pragma unroll
        for (int p = 0; p < 8; ++p) {
            int row = p * 8 + srow;
            f32x4 v = __builtin_nontemporal_load(
                (const f32x4*)&x[(size_t)(token0 + row) * 1024 + k0 + scol]);
            *(f32x4*)&xs[row * XSTR + scol] = v;
        }
        __syncthreads();
        // ---- compute ----
        const float* arow = &xs[(wid * 16 + nn) * XSTR + qsel * 8];
#pragma unroll
        for (int kc = 0; kc < 4; ++kc) {
            float xv[8];
            *(f32x4*)&xv[0] = *(const f32x4*)(arow + kc * 32);
            *(f32x4*)&xv[4] = *(const f32x4*)(arow + kc * 32 + 4);
            short8 ah, al;
            split8(xv, ah, al);
            const int kchunk = t * 4 + kc;
            const short* bh = bswH + (size_t)(kchunk * 4) * 512 + lane * 8;
            const short* bl = bswL + (size_t)(kchunk * 4) * 512 + lane * 8;
#pragma unroll
            for (int et = 0; et < 4; ++et) {
                short8 b_h = *(const short8*)(bh + et * 512);
                short8 b_l = *(const short8*)(bl + et * 512);
                acc[et] = __builtin_amdgcn_mfma_f32_16x16x32_bf16(ah, b_h, acc[et], 0, 0, 0);
                acc[et] = __builtin_amdgcn_mfma_f32_16x16x32_bf16(ah, b_l, acc[et], 0, 0, 0);
                acc[et] = __builtin_amdgcn_mfma_f32_16x16x32_bf16(al, b_h, acc[et], 0, 0, 0);
            }
        }
        __syncthreads();
    }

    // ---- epilogue: logits into reused xs tile [tok][e] (stride ROWP) ----
    const int q4 = qsel * 4;
#pragma unroll
    for (int et = 0; et < 4; ++et) {
        float lb = (float)lbias64[b * 64 + et * 16 + nn];
#pragma unroll
        for (int r = 0; r < 4; ++r) {
            int tok = wid * 16 + q4 + r;
            xs[tok * ROWP + et * 16 + nn] = acc[et][r] + lb;
        }
    }
    __syncthreads();

    if (tid < MT) {
        const int t = tid;
        const int base = t * ROWP;
        float v1 = -1e30f, v2 = -1e30f, v3 = -1e30f;
        int i1 = 0, i2 = 0;
        for (int e = 0; e < E_; ++e) {
            float l = xs[base + e];
            if (l > v1)      { v3 = v2; v2 = v1; i2 = i1; v1 = l; i1 = e; }
            else if (l > v2) { v3 = v2; v2 = l; i2 = e; }
            else if (l > v3) { v3 = l; }
        }
        float sum = 0.f;
        for (int e = 0; e < E_; ++e) {
            float ex = __expf(xs[base + e] - v1);
            xs[base + e] = ex;
            sum += ex;
        }
        invs[t] = 1.0f / sum;

        const int gt = token0 + t;
        float s1 = 1.0f / (1.0f + __expf(v2 - v1));   // softmax over top-2
        *(float2*)&out[OFF_IDX + (size_t)gt * 2]    = make_float2((float)i1, (float)i2);
        *(float2*)&out[OFF_SCORES + (size_t)gt * 2] = make_float2(s1, 1.0f - s1);
        atomicAdd(&cnts[i1], 1u);
        atomicAdd(&cnts[i2], 1u);

        float g12 = v1 - v2, g23 = v2 - v3;
        float g = g12 < g23 ? g12 : g23;
        if (g < REFINE_EPS) {
            unsigned int pos = atomicAdd(ref_cnt, 1u);
            if (pos < REFINE_CAP) ref_list[pos] = gt;
        }
    }
    __syncthreads();

    // probs: 4096 floats = 1024 float4, coalesced
    float* probs = out + OFF_PROBS + (size_t)token0 * E_;
#pragma unroll
    for (int k = 0; k < 4; ++k) {
        int li4 = tid + k * 256;
        int tok = li4 >> 4;
        int c4 = (li4 & 15) << 2;
        float inv = invs[tok];
        int o = tok * ROWP + c4;
        *(float4*)&probs[(size_t)li4 * 4] =
            make_float4(xs[o] * inv, xs[o + 1] * inv,
                        xs[o + 2] * inv, xs[o + 3] * inv);
    }

    // importance + load: one atomic each per e per block
    if (tid < E_) {
        const int e = tid;
        float s = 0.f;
        for (int t = 0; t < MT; ++t) s += xs[t * ROWP + e] * invs[t];
        atomicAdd(&out[OFF_IMP + e],  s * (1.0f / (float)NTOK));
        atomicAdd(&out[OFF_LOAD + e], (float)cnts[e] * (1.0f / (float)(NTOK * KSEL)));
    }
}

// ---------------------------------------------------------------------------
// K_ref: fp64 re-evaluation of ambiguous tokens. One wave per flagged token,
// lane = expert, 4 split accumulators.
// ---------------------------------------------------------------------------
__global__ __launch_bounds__(256) void k_refine(const float* __restrict__ x,
                                                const float* __restrict__ wcomb32,
                                                const double* __restrict__ lbias64,
                                                const unsigned int* __restrict__ ref_cnt,
                                                const int* __restrict__ ref_list,
                                                float* __restrict__ out) {
    int wave = (int)((blockIdx.x * blockDim.x + threadIdx.x) >> 6);
    int lane = threadIdx.x & 63;
    unsigned int n = *ref_cnt;
    if (n > REFINE_CAP) n = REFINE_CAP;
    const int nwaves = (int)((gridDim.x * blockDim.x) >> 6);

    for (unsigned int wi = wave; wi < n; wi += nwaves) {
        const int gt = ref_list[wi];
        const int b = gt / T_;
        const float* xrow = x + (size_t)gt * C_;
        double a0 = 0.0, a1 = 0.0, a2 = 0.0, a3 = 0.0;
        for (int d = 0; d < C_; d += 4) {
            a0 += (double)xrow[d + 0] * (double)wcomb32[(d + 0) * 64 + lane];
            a1 += (double)xrow[d + 1] * (double)wcomb32[(d + 1) * 64 + lane];
            a2 += (double)xrow[d + 2] * (double)wcomb32[(d + 2) * 64 + lane];
            a3 += (double)xrow[d + 3] * (double)wcomb32[(d + 3) * 64 + lane];
        }
        double acc = ((a0 + a1) + (a2 + a3)) + lbias64[b * 64 + lane];

        double v = acc; int id = lane;
        for (int off = 32; off > 0; off >>= 1) {
            double ov = __shfl_xor(v, off, 64);
            int oid   = __shfl_xor(id, off, 64);
            if (ov > v || (ov == v && oid < id)) { v = ov; id = oid; }
        }
        double v1 = v; int i1 = id;
        v = (lane == i1) ? -1e300 : acc; id = lane;
        for (int off = 32; off > 0; off >>= 1) {
            double ov = __shfl_xor(v, off, 64);
            int oid   = __shfl_xor(id, off, 64);
            if (ov > v || (ov == v && oid < id)) { v = ov; id = oid; }
        }
        double v2 = v; int i2 = id;

        if (lane == 0) {
            float s1 = (float)(1.0 / (1.0 + exp(v2 - v1)));
            *(float2*)&out[OFF_IDX + (size_t)gt * 2]    = make_float2((float)i1, (float)i2);
            *(float2*)&out[OFF_SCORES + (size_t)gt * 2] = make_float2(s1, 1.0f - s1);
        }
    }
}

// ---------------------------------------------------------------------------
extern "C" void kernel_launch(void* const* d_in, const int* in_sizes, int n_in,
                              void* d_out, int out_size, void* d_ws, size_t ws_size,
                              hipStream_t stream) {
    const float* x    = (const float*)d_in[0];   // (4,8192,1024)
    const float* cond = (const float*)d_in[1];   // (4,1024)
    const float* Wg   = (const float*)d_in[2];   // (64,1024)
    const float* Wc   = (const float*)d_in[3];   // (1024,2048)
    float* out = (float*)d_out;
    char*  ws  = (char*)d_ws;

    float*  wcomb32 = (float*)(ws + WS_W32);
    short*  bswH    = (short*)(ws + WS_BSWH);
    short*  bswL    = (short*)(ws + WS_BSWL);
    double* lbias64 = (double*)(ws + WS_LB64);
    unsigned int* ref_cnt = (unsigned int*)(ws + WS_CNT);
    int*    ref_list = (int*)(ws + WS_LIST);

    // zero lbias64 (2 KB) + ref_cnt (adjacent) in one memset
    hipMemsetAsync(ws + WS_LB64, 0, (WS_CNT - WS_LB64) + 64, stream);

    k_prep<<<256, 256, 0, stream>>>(Wg, Wc, cond, wcomb32, bswH, bswL, lbias64, out);
    k_main<<<NTOK / MT, 256, 0, stream>>>(x, bswH, bswL, lbias64, out, ref_cnt, ref_list);
    k_refine<<<128, 256, 0, stream>>>(x, wcomb32, lbias64, ref_cnt, ref_list, out);
}